// Round 1
// baseline (589.994 us; speedup 1.0000x reference)
//
#include <hip/hip_runtime.h>
#include <hip/hip_bf16.h>
#include <stdint.h>

// MPNN latency predictor, MI355X — round 8.
// vs R7: k_msg_fused restructured from edge-split waves (B-frag read once per
// MFMA -> LDS-bound at ~2.5x, 17 barrier drains) to kk-split waves:
//  * each wave owns all 64 edges (4 M-tiles) and a 16-kk K-slice; B-frags are
//    register-reused x4 -> LDS read volume /4 (under the 85 B/cyc ceiling).
//  * A-frags are STATIC bf16 rows of hb (no per-kk packA); hid[e,kk] is folded
//    in post-MFMA as v_fmac on the 16 C elements (fewer VALU, one less bf16
//    rounding).
//  * wave-private double-buffered staging + per-wave counted s_waitcnt
//    vmcnt(8): ZERO barriers in the main loop (was 17 full drains).
//  * hid is now stored transposed (hidT: 64 x E) so per-kk hv rows are
//    coalesced; staged once into a small per-wave LDS strip.
//  * 4 kk-partials reduced through LDS (stride-66 pad), then the same 4096
//    atomicAdds per block as before.

#define N_NODES 32768
#define N_EDGES 32768
#define STEPS 3

typedef __attribute__((ext_vector_type(8))) short short8;   // 8 bf16 = 4 VGPRs
typedef __attribute__((ext_vector_type(4))) float float4v;  // MFMA C/D

__device__ __forceinline__ float bf2f(unsigned short u) {
    union { unsigned int i; float f; } v; v.i = ((unsigned int)u) << 16; return v.f;
}
__device__ __forceinline__ unsigned short f2bf(float f) {  // RNE
    union { float f; unsigned int i; } v; v.f = f;
    unsigned int x = v.i;
    return (unsigned short)((x + 0x7fffu + ((x >> 16) & 1u)) >> 16);
}

// async global->LDS, 16B/lane; lds dest = wave-uniform base + lane*16
__device__ __forceinline__ void gload_lds16(const void* g, void* l) {
    __builtin_amdgcn_global_load_lds(
        (__attribute__((address_space(1))) void*)g,
        (__attribute__((address_space(3))) void*)l, 16, 0, 0);
}

// ===================== fused setup kernel ==================================
// blockIdx segments:
//  [0,144)       rootTf (4096) + wcombf (32768)      — frag-interleaved
//  [144,1184)    w2tf (266240 valid + 4096 pad)       — frag-interleaved
//  [1184,1232)   wd1f (10240) + wd2f (2048)           — frag-interleaved
//  [1232,9424)   proj: hb = bf16(tanh([x,u]@Wp^T+bp))
//  [9424,17616)  edge hidden TRANSPOSED: hidT[j][e] = relu(ea@We1^T+be1)
//  [17616,19696) zero aggcnt (2129920 floats, float4 stores)
__global__ __launch_bounds__(256) void k_setup(
    const float* __restrict__ root, const float* __restrict__ Wih,
    const float* __restrict__ Whh,
    const float* __restrict__ We2, const float* __restrict__ be2,
    const float* __restrict__ Wd1, const float* __restrict__ bd1,
    const float* __restrict__ Wd2,
    const float* __restrict__ x, const float* __restrict__ u,
    const float* __restrict__ Wp, const float* __restrict__ bp,
    const float* __restrict__ ea, const float* __restrict__ We1,
    const float* __restrict__ be1,
    unsigned short* __restrict__ rootTf, unsigned short* __restrict__ wcombf,
    unsigned short* __restrict__ w2tf,
    unsigned short* __restrict__ wd1f, unsigned short* __restrict__ wd2f,
    unsigned short* __restrict__ hb,
    unsigned short* __restrict__ hidT, float* __restrict__ aggcnt)
{
    int b = blockIdx.x, tid = threadIdx.x;
    if (b < 144) {
        int i = b * 256 + tid;
        if (i < 4096) {
            int j = i & 7, lane = (i >> 3) & 63, g = i >> 9;   // g<8
            int kb = g >> 2, nf = g & 3;
            int o = nf * 16 + (lane & 15);
            int k = kb * 32 + (lane >> 4) * 8 + j;
            rootTf[i] = f2bf(root[k * 64 + o]);
        } else if (i < 4096 + 32768) {
            int t = i - 4096;
            int j = t & 7, lane = (t >> 3) & 63, g = t >> 9;   // g<64
            int kb = g >> 4, nf = g & 15;
            int cp = nf * 16 + (lane & 15);
            int k = kb * 32 + (lane >> 4) * 8 + j;
            float v;
            if (cp < 128)      v = (k < 64) ? Wih[cp * 64 + k] : Whh[cp * 64 + (k - 64)];
            else if (cp < 192) v = (k < 64) ? Wih[cp * 64 + k] : 0.f;
            else               v = (k < 64) ? 0.f : Whh[(cp - 64) * 64 + (k - 64)];
            wcombf[t] = f2bf(v);
        }
    } else if (b < 1184) {
        int t = (b - 144) * 256 + tid;   // t < 266240
        if (t < 65 * 4096) {
            int kk = t >> 12, r = t & 4095;
            int j = r & 7, lane = (r >> 3) & 63, g = r >> 9;  // g<8
            int half = g >> 2, nf = g & 3;
            int o = nf * 16 + (lane & 15);
            int hh = half * 32 + (lane >> 4) * 8 + j;
            float v = (kk < 64) ? We2[((size_t)(hh * 64 + o)) * 64 + kk]
                                : be2[(size_t)hh * 64 + o];
            w2tf[t] = f2bf(v);
        }
    } else if (b < 1232) {
        int i = (b - 1184) * 256 + tid;
        if (i < 10240) {
            int j = i & 7, lane = (i >> 3) & 63, g = i >> 9;  // g<20
            int kb = g >> 2, nf = g & 3;
            int o = nf * 16 + (lane & 15);
            int k = kb * 32 + (lane >> 4) * 8 + j;
            float v = (k < 133) ? Wd1[(size_t)o * 133 + k] : (k == 133 ? bd1[o] : 0.f);
            wd1f[i] = f2bf(v);
        } else if (i < 10240 + 2048) {
            int t = i - 10240;
            int j = t & 7, lane = (t >> 3) & 63, g = t >> 9;  // g<4
            int kb = g >> 1, nf = g & 1;
            int o = nf * 16 + (lane & 15);
            int k = kb * 32 + (lane >> 4) * 8 + j;
            wd2f[t] = f2bf(Wd2[(size_t)o * 64 + k]);
        }
    } else if (b < 9424) {
        int idx = (b - 1232) * 256 + tid;
        int n = idx >> 6, j = idx & 63;
        const float* wr = Wp + j * 23;
        const float* xr = x + (size_t)n * 12;
        float s = bp[j];
#pragma unroll
        for (int i = 0; i < 12; i++) s += xr[i] * wr[i];
#pragma unroll
        for (int i = 0; i < 11; i++) s += u[i] * wr[12 + i];
        hb[idx] = f2bf(tanhf(s));
    } else if (b < 17616) {
        int idx = (b - 9424) * 256 + tid;           // idx < 2^21
        int el = idx & 63, j = (idx >> 6) & 63, eb = idx >> 12;
        int e = eb * 64 + el;                       // lane-varying e -> coalesced
        float s = be1[j];
#pragma unroll
        for (int i = 0; i < 5; i++) s += ea[(size_t)e * 5 + i] * We1[j * 5 + i];
        hidT[(size_t)j * N_EDGES + e] = f2bf(s > 0.f ? s : 0.f);
    } else {
        int idx = (b - 17616) * 1024 + tid * 4;
        if (idx < 2129920) {
            float4v z = {0.f, 0.f, 0.f, 0.f};
            *(float4v*)(aggcnt + idx) = z;
        }
    }
}

__global__ __launch_bounds__(256) void k_counts(
    const int* __restrict__ ei, float* __restrict__ counts)
{
    int i = blockIdx.x * 256 + threadIdx.x;
    if (i < N_EDGES) atomicAdd(&counts[ei[N_EDGES + i]], 1.0f);
}

// ===================== fused msg GEMM ======================================
// 256 threads = 4 waves, 64 edges/block, grid 512 (2 blocks/CU, LDS 72KB).
// Wave w owns kk-slice w*16..w*16+15 (wave 3 also kk=64 = bias row, hv=1).
// Per kk: T[tile] = Hsrc(16x64) @ W2[kk](64x64) via 8 MFMA with STATIC bf16
// A-frags; acc += hid[e,kk] * T (v_fmac). B-frags reused across 4 M-tiles.
// Wave-private dbuf staging, counted vmcnt, no barriers until the reduce.
__global__ __launch_bounds__(256, 2) void k_msg_fused(
    const unsigned short* __restrict__ hidT,  // (64, E) bf16
    const unsigned short* __restrict__ hb,    // (N,64) bf16
    const unsigned short* __restrict__ w2tf,  // (66*4096) frag-interleaved
    const int* __restrict__ ei,
    float* __restrict__ agg)
{
    // LDS map: [0,65536) staging 4 waves x 2 dbuf x 8192B
    //          [65536,73728) hv strip: 4 waves x 16 r x 64 e bf16
    //          reduce overlay (after loop): [0,67584) 4 x 64 x 66 f32
    __shared__ __attribute__((aligned(16))) unsigned char smem[73728];
    unsigned short* stg = (unsigned short*)smem;
    unsigned short* hvl = (unsigned short*)(smem + 65536);
    float* red = (float*)smem;

    int tid = threadIdx.x, w = tid >> 6, lane = tid & 63;
    int l15 = lane & 15, quad = lane >> 4;
    int ebase = blockIdx.x * 64;
    int n = 16 + (w == 3 ? 1 : 0);   // wave 3 takes the bias row kk=64

    // ---- preamble: hv rows (coalesced 128B each) -> per-wave LDS strip ----
    {
        const unsigned short* hp = hidT + (size_t)(w * 16) * N_EDGES + ebase + lane;
        unsigned short* dp = hvl + (w * 16) * 64 + lane;
#pragma unroll
        for (int r = 0; r < 16; r++)
            dp[r * 64] = hp[(size_t)r * N_EDGES];
    }
    // ---- static A-frags: 4 edge-tiles x 2 K-halves of h[src] (bf16) ----
    short8 afr[4][2];
#pragma unroll
    for (int t = 0; t < 4; t++) {
        int src = ei[ebase + t * 16 + l15];
#pragma unroll
        for (int hh = 0; hh < 2; hh++)
            afr[t][hh] = *(const short8*)(hb + (size_t)src * 64 + hh * 32 + quad * 8);
    }

    unsigned short* wbuf = stg + w * (2 * 4096);
    auto stage = [&](int r, int db) {
        const unsigned short* g = w2tf + (size_t)(w * 16 + r) * 4096;
        unsigned short* d = wbuf + db * 4096;
#pragma unroll
        for (int c = 0; c < 8; c++)
            gload_lds16(g + c * 512 + lane * 8, d + c * 512);
    };

    stage(0, 0);
    stage(1, 1);

    float4v acc[4][4] = {};   // [tile][nf]
    for (int r = 0; r < n; r++) {
        int db = r & 1;
        // stage r complete when the newest 8 (stage r+1) may still be in flight
        if (r < n - 1) { asm volatile("s_waitcnt vmcnt(8)" ::: "memory"); }
        else           { asm volatile("s_waitcnt vmcnt(0)" ::: "memory"); }

        // B-frags for this kk (reused across the 4 M-tiles)
        short8 bfr[2][4];
        const unsigned short* bb = wbuf + db * 4096;
#pragma unroll
        for (int hh = 0; hh < 2; hh++)
#pragma unroll
            for (int nf = 0; nf < 4; nf++)
                bfr[hh][nf] = *(const short8*)(bb + (hh * 4 + nf) * 512 + lane * 8);

        // hv: 4 bf16 per tile (rows quad*4..+3), broadcast across l15
        bool bias = (r == 16);
        unsigned long long hu[4] = {0ull, 0ull, 0ull, 0ull};
        if (!bias) {
#pragma unroll
            for (int t = 0; t < 4; t++)
                hu[t] = *(const unsigned long long*)(hvl + (w * 16 + r) * 64 + t * 16 + quad * 4);
        }

        // all LDS reads done before overwriting buffer db with stage r+2
        asm volatile("s_waitcnt lgkmcnt(0)" ::: "memory");
        if (r + 2 < n) stage(r + 2, db);

#pragma unroll
        for (int t = 0; t < 4; t++) {
            float4v T[4];
#pragma unroll
            for (int nf = 0; nf < 4; nf++) {
                float4v z = {0.f, 0.f, 0.f, 0.f};
                T[nf] = __builtin_amdgcn_mfma_f32_16x16x32_bf16(afr[t][0], bfr[0][nf], z, 0, 0, 0);
            }
#pragma unroll
            for (int nf = 0; nf < 4; nf++)
                T[nf] = __builtin_amdgcn_mfma_f32_16x16x32_bf16(afr[t][1], bfr[1][nf], T[nf], 0, 0, 0);
#pragma unroll
            for (int rr = 0; rr < 4; rr++) {
                float hvv = bias ? 1.0f : bf2f((unsigned short)(hu[t] >> (16 * rr)));
#pragma unroll
                for (int nf = 0; nf < 4; nf++)
                    acc[t][nf][rr] += hvv * T[nf][rr];
            }
        }
    }

    // ---- cross-wave reduce (4 partials) + atomic scatter ----
    __syncthreads();   // everyone done reading/staging LDS
    float* rp = red + w * 4224;                 // 64 rows x stride 66
#pragma unroll
    for (int t = 0; t < 4; t++)
#pragma unroll
        for (int nf = 0; nf < 4; nf++)
#pragma unroll
            for (int rr = 0; rr < 4; rr++)
                rp[(t * 16 + quad * 4 + rr) * 66 + nf * 16 + l15] = acc[t][nf][rr];
    __syncthreads();
    {
        int row = tid >> 2, c0 = (tid & 3) * 16;
        int dst = ei[N_EDGES + ebase + row];
        float* ap = agg + (size_t)dst * 64 + c0;
#pragma unroll
        for (int k = 0; k < 16; k++) {
            float s = 0.f;
#pragma unroll
            for (int ww = 0; ww < 4; ww++)
                s += red[ww * 4224 + row * 66 + c0 + k];
            atomicAdd(ap + k, s);
        }
    }
}

// ===================== fused node update ===================================
// h_old comes from hb (bf16) — fp32 h array eliminated.
__global__ __launch_bounds__(256) void k_node(
    const unsigned short* __restrict__ hb_in,
    const unsigned short* __restrict__ rootTf,
    const unsigned short* __restrict__ wcombf,
    float* __restrict__ agg, const float* __restrict__ counts,
    const float* __restrict__ conv_b,
    const float* __restrict__ bih, const float* __restrict__ bhh,
    unsigned short* __restrict__ hb_out)
{
    __shared__ unsigned short m_lds[64 * 72];
    int tid = threadIdx.x, w = tid >> 6, lane = tid & 63;
    int l15 = lane & 15, quad = lane >> 4;
    int node0 = blockIdx.x * 64;
    int row0 = w * 16;

    float4v acc1[4] = {};
    {
        short8 a1[2];
#pragma unroll
        for (int kb = 0; kb < 2; kb++)
            a1[kb] = *(const short8*)(hb_in + (size_t)(node0 + row0 + l15) * 64 + kb * 32 + quad * 8);
#pragma unroll
        for (int kb = 0; kb < 2; kb++)
#pragma unroll
            for (int nf = 0; nf < 4; nf++) {
                short8 b = *(const short8*)(rootTf + (size_t)((kb * 4 + nf) * 64 + lane) * 8);
                acc1[nf] = __builtin_amdgcn_mfma_f32_16x16x32_bf16(a1[kb], b, acc1[nf], 0, 0, 0);
            }
    }
#pragma unroll
    for (int rr = 0; rr < 4; rr++) {
        int nl = row0 + quad * 4 + rr;
        float cnt = counts[node0 + nl]; if (cnt < 1.f) cnt = 1.f;
        float rcp = 1.f / cnt;
#pragma unroll
        for (int nf = 0; nf < 4; nf++) {
            int c = nf * 16 + l15;
            float* ap = agg + (size_t)(node0 + nl) * 64 + c;
            float av = *ap;
            *ap = 0.f;
            float mv = av * rcp + acc1[nf][rr] + conv_b[c];
            m_lds[nl * 72 + c] = f2bf(mv > 0.f ? mv : 0.f);
        }
    }
    __syncthreads();

    float4v acc2[16] = {};
#pragma unroll
    for (int kb = 0; kb < 4; kb++) {
        short8 a2;
        if (kb < 2)
            a2 = *(const short8*)(m_lds + (row0 + l15) * 72 + kb * 32 + quad * 8);
        else
            a2 = *(const short8*)(hb_in + (size_t)(node0 + row0 + l15) * 64 + (kb - 2) * 32 + quad * 8);
#pragma unroll
        for (int nf = 0; nf < 16; nf++) {
            short8 b = *(const short8*)(wcombf + (size_t)((kb * 16 + nf) * 64 + lane) * 8);
            acc2[nf] = __builtin_amdgcn_mfma_f32_16x16x32_bf16(a2, b, acc2[nf], 0, 0, 0);
        }
    }

#pragma unroll
    for (int nf0 = 0; nf0 < 4; nf0++) {
        int c = nf0 * 16 + l15;
        float br = bih[c] + bhh[c];
        float bz = bih[64 + c] + bhh[64 + c];
        float bni = bih[128 + c], bnh = bhh[128 + c];
#pragma unroll
        for (int rr = 0; rr < 4; rr++) {
            int node = node0 + row0 + quad * 4 + rr;
            float gr = 1.f / (1.f + __expf(-(acc2[nf0][rr] + br)));
            float gz = 1.f / (1.f + __expf(-(acc2[nf0 + 4][rr] + bz)));
            float ng = tanhf(acc2[nf0 + 8][rr] + bni + gr * (acc2[nf0 + 12][rr] + bnh));
            float ho = bf2f(hb_in[(size_t)node * 64 + c]);
            float hn = (1.f - gz) * ng + gz * ho;
            hb_out[(size_t)node * 64 + c] = f2bf(hn);
        }
    }
}

// ===================== MFMA decoder ========================================
__global__ __launch_bounds__(256) void k_decoder(
    const unsigned short* __restrict__ hb, const int* __restrict__ ei,
    const float* __restrict__ ea,
    const unsigned short* __restrict__ wd1f, const unsigned short* __restrict__ wd2f,
    const float* __restrict__ bd2,
    const float* __restrict__ Wd3, const float* __restrict__ bd3,
    float* __restrict__ out)
{
    __shared__ unsigned short d1f[4][1024];  // per-wave: 2 frags x 512
    __shared__ float d2s[4][16 * 33];        // per-wave: 16 edges x 32 (+pad)
    int tid = threadIdx.x, w = tid >> 6, lane = tid & 63;
    int l15 = lane & 15, quad = lane >> 4;
    int ebase = blockIdx.x * 64 + w * 16;
    int e = ebase + l15;
    int src = ei[e], dst = ei[N_EDGES + e];

    short8 a[5];
#pragma unroll
    for (int kb = 0; kb < 2; kb++) {
        a[kb]     = *(const short8*)(hb + (size_t)src * 64 + kb * 32 + quad * 8);
        a[2 + kb] = *(const short8*)(hb + (size_t)dst * 64 + kb * 32 + quad * 8);
    }
    {
        union { short8 v; unsigned short u[8]; } tea;
#pragma unroll
        for (int j = 0; j < 8; j++) {
            float vv = 0.f;
            if (quad == 0) vv = (j < 5) ? ea[(size_t)e * 5 + j] : (j == 5 ? 1.f : 0.f);
            tea.u[j] = f2bf(vv);
        }
        a[4] = tea.v;
    }

    float4v acc1[4] = {};
#pragma unroll
    for (int kb = 0; kb < 5; kb++)
#pragma unroll
        for (int nf = 0; nf < 4; nf++) {
            short8 b = *(const short8*)(wd1f + (size_t)((kb * 4 + nf) * 64 + lane) * 8);
            acc1[nf] = __builtin_amdgcn_mfma_f32_16x16x32_bf16(a[kb], b, acc1[nf], 0, 0, 0);
        }
#pragma unroll
    for (int nf = 0; nf < 4; nf++) {
        int kbp = nf >> 1;
        int lanep_hi = ((nf & 1) * 2 + (l15 >> 3)) * 16;
        int jp = l15 & 7;
#pragma unroll
        for (int r = 0; r < 4; r++) {
            float v = acc1[nf][r];
            d1f[w][kbp * 512 + (lanep_hi + quad * 4 + r) * 8 + jp] = f2bf(v > 0.f ? v : 0.f);
        }
    }
    float4v acc2[2] = {};
#pragma unroll
    for (int kb = 0; kb < 2; kb++) {
        short8 a2 = *(const short8*)(&d1f[w][kb * 512 + lane * 8]);
#pragma unroll
        for (int nf = 0; nf < 2; nf++) {
            short8 b = *(const short8*)(wd2f + (size_t)((kb * 2 + nf) * 64 + lane) * 8);
            acc2[nf] = __builtin_amdgcn_mfma_f32_16x16x32_bf16(a2, b, acc2[nf], 0, 0, 0);
        }
    }
#pragma unroll
    for (int nf = 0; nf < 2; nf++) {
        int c = nf * 16 + l15;
        float bias = bd2[c];
#pragma unroll
        for (int r = 0; r < 4; r++) {
            float v = acc2[nf][r] + bias;
            d2s[w][(quad * 4 + r) * 33 + c] = v > 0.f ? v : 0.f;
        }
    }
    {
        int e_l = lane >> 2, t = lane & 3;
        float s = bd3[t];
        const float* w3 = Wd3 + t * 32;
        const float* dr = &d2s[w][e_l * 33];
#pragma unroll
        for (int k = 0; k < 32; k++) s += w3[k] * dr[k];
        out[(size_t)(ebase + e_l) * 4 + t] = s;
    }
}

extern "C" void kernel_launch(void* const* d_in, const int* in_sizes, int n_in,
                              void* d_out, int out_size, void* d_ws, size_t ws_size,
                              hipStream_t stream)
{
    const float* x      = (const float*)d_in[0];
    const int*   ei     = (const int*)d_in[1];
    const float* ea     = (const float*)d_in[2];
    const float* u      = (const float*)d_in[3];
    const float* Wp     = (const float*)d_in[4];
    const float* bp     = (const float*)d_in[5];
    const float* We1    = (const float*)d_in[6];
    const float* be1    = (const float*)d_in[7];
    const float* We2    = (const float*)d_in[8];
    const float* be2    = (const float*)d_in[9];
    const float* root   = (const float*)d_in[10];
    const float* conv_b = (const float*)d_in[11];
    const float* Wih    = (const float*)d_in[12];
    const float* bih    = (const float*)d_in[13];
    const float* Whh    = (const float*)d_in[14];
    const float* bhh    = (const float*)d_in[15];
    const float* Wd1    = (const float*)d_in[16];
    const float* bd1    = (const float*)d_in[17];
    const float* Wd2    = (const float*)d_in[18];
    const float* bd2    = (const float*)d_in[19];
    const float* Wd3    = (const float*)d_in[20];
    const float* bd3    = (const float*)d_in[21];
    float* out = (float*)d_out;

    char* ws = (char*)d_ws;
    size_t off = 0;
    auto take = [&](size_t bytes) -> char* {
        char* p = ws + off; off = (off + bytes + 255) & ~(size_t)255; return p;
    };
    unsigned short* hb     = (unsigned short*)take((size_t)N_NODES * 64 * 2);
    unsigned short* hidT   = (unsigned short*)take((size_t)N_EDGES * 64 * 2);
    // agg (2097152 f) and cnts (32768 f) contiguous: zeroed together in setup
    float*          aggcnt = (float*)take((size_t)(N_NODES * 64 + N_NODES) * 4);
    float*          agg    = aggcnt;
    float*          cnts   = aggcnt + (size_t)N_NODES * 64;
    unsigned short* w2tf   = (unsigned short*)take((size_t)66 * 4096 * 2);  // +1 pad blk
    unsigned short* rootTf = (unsigned short*)take((size_t)4096 * 2);
    unsigned short* wcombf = (unsigned short*)take((size_t)32768 * 2);
    unsigned short* wd1f   = (unsigned short*)take((size_t)10240 * 2);
    unsigned short* wd2f   = (unsigned short*)take((size_t)2048 * 2);
    (void)ws_size;

    k_setup<<<19696, 256, 0, stream>>>(root, Wih, Whh, We2, be2, Wd1, bd1, Wd2,
                                       x, u, Wp, bp, ea, We1, be1,
                                       rootTf, wcombf, w2tf, wd1f, wd2f,
                                       hb, hidT, aggcnt);
    k_counts<<<128, 256, 0, stream>>>(ei, cnts);

    for (int s = 0; s < STEPS; s++) {
        k_msg_fused<<<N_EDGES / 64, 256, 0, stream>>>(hidT, hb, w2tf, ei, agg);
        k_node<<<N_NODES / 64, 256, 0, stream>>>(hb, rootTf, wcombf, agg, cnts,
                                                 conv_b, bih, bhh, hb);
    }
    k_decoder<<<N_EDGES / 64, 256, 0, stream>>>(hb, ei, ea, wd1f, wd2f, bd2,
                                                Wd3, bd3, out);
}

// Round 2
// 260.124 us; speedup vs baseline: 2.2681x; 2.2681x over previous
//
#include <hip/hip_runtime.h>
#include <hip/hip_bf16.h>
#include <stdint.h>

// MPNN latency predictor, MI355X — round 9.
// vs R8 (589µs regression): post-mortem found the killer in the NEW atomic
// scatter layout, not the kk-split loop. R8's reduce gave each atomic
// instruction 64 lanes on 64 DIFFERENT agg rows -> 1024 line-RMWs per wave,
// 2M x 32B sector writebacks (WRITE_SIZE was exactly 65536KB = 2^21 x 32B).
// R9 restores the R7-style wave-coalesced scatter: per instruction, lanes
// cover 4 rows x 16 consecutive floats = 4 full 64B lines -> L2 merges the
// 16 lanes of each line into one RMW (~16x fewer line transactions).
// Everything else (kk-split waves, static bf16 A-frags, B-frag reuse x4,
// wave-private dbuf staging with counted vmcnt, zero main-loop barriers)
// is unchanged from R8.

#define N_NODES 32768
#define N_EDGES 32768
#define STEPS 3

typedef __attribute__((ext_vector_type(8))) short short8;   // 8 bf16 = 4 VGPRs
typedef __attribute__((ext_vector_type(4))) float float4v;  // MFMA C/D

__device__ __forceinline__ float bf2f(unsigned short u) {
    union { unsigned int i; float f; } v; v.i = ((unsigned int)u) << 16; return v.f;
}
__device__ __forceinline__ unsigned short f2bf(float f) {  // RNE
    union { float f; unsigned int i; } v; v.f = f;
    unsigned int x = v.i;
    return (unsigned short)((x + 0x7fffu + ((x >> 16) & 1u)) >> 16);
}

// async global->LDS, 16B/lane; lds dest = wave-uniform base + lane*16
__device__ __forceinline__ void gload_lds16(const void* g, void* l) {
    __builtin_amdgcn_global_load_lds(
        (__attribute__((address_space(1))) void*)g,
        (__attribute__((address_space(3))) void*)l, 16, 0, 0);
}

// ===================== fused setup kernel ==================================
// blockIdx segments:
//  [0,144)       rootTf (4096) + wcombf (32768)      — frag-interleaved
//  [144,1184)    w2tf (266240 valid + 4096 pad)       — frag-interleaved
//  [1184,1232)   wd1f (10240) + wd2f (2048)           — frag-interleaved
//  [1232,9424)   proj: hb = bf16(tanh([x,u]@Wp^T+bp))
//  [9424,17616)  edge hidden TRANSPOSED: hidT[j][e] = relu(ea@We1^T+be1)
//  [17616,19696) zero aggcnt (2129920 floats, float4 stores)
__global__ __launch_bounds__(256) void k_setup(
    const float* __restrict__ root, const float* __restrict__ Wih,
    const float* __restrict__ Whh,
    const float* __restrict__ We2, const float* __restrict__ be2,
    const float* __restrict__ Wd1, const float* __restrict__ bd1,
    const float* __restrict__ Wd2,
    const float* __restrict__ x, const float* __restrict__ u,
    const float* __restrict__ Wp, const float* __restrict__ bp,
    const float* __restrict__ ea, const float* __restrict__ We1,
    const float* __restrict__ be1,
    unsigned short* __restrict__ rootTf, unsigned short* __restrict__ wcombf,
    unsigned short* __restrict__ w2tf,
    unsigned short* __restrict__ wd1f, unsigned short* __restrict__ wd2f,
    unsigned short* __restrict__ hb,
    unsigned short* __restrict__ hidT, float* __restrict__ aggcnt)
{
    int b = blockIdx.x, tid = threadIdx.x;
    if (b < 144) {
        int i = b * 256 + tid;
        if (i < 4096) {
            int j = i & 7, lane = (i >> 3) & 63, g = i >> 9;   // g<8
            int kb = g >> 2, nf = g & 3;
            int o = nf * 16 + (lane & 15);
            int k = kb * 32 + (lane >> 4) * 8 + j;
            rootTf[i] = f2bf(root[k * 64 + o]);
        } else if (i < 4096 + 32768) {
            int t = i - 4096;
            int j = t & 7, lane = (t >> 3) & 63, g = t >> 9;   // g<64
            int kb = g >> 4, nf = g & 15;
            int cp = nf * 16 + (lane & 15);
            int k = kb * 32 + (lane >> 4) * 8 + j;
            float v;
            if (cp < 128)      v = (k < 64) ? Wih[cp * 64 + k] : Whh[cp * 64 + (k - 64)];
            else if (cp < 192) v = (k < 64) ? Wih[cp * 64 + k] : 0.f;
            else               v = (k < 64) ? 0.f : Whh[(cp - 64) * 64 + (k - 64)];
            wcombf[t] = f2bf(v);
        }
    } else if (b < 1184) {
        int t = (b - 144) * 256 + tid;   // t < 266240
        if (t < 65 * 4096) {
            int kk = t >> 12, r = t & 4095;
            int j = r & 7, lane = (r >> 3) & 63, g = r >> 9;  // g<8
            int half = g >> 2, nf = g & 3;
            int o = nf * 16 + (lane & 15);
            int hh = half * 32 + (lane >> 4) * 8 + j;
            float v = (kk < 64) ? We2[((size_t)(hh * 64 + o)) * 64 + kk]
                                : be2[(size_t)hh * 64 + o];
            w2tf[t] = f2bf(v);
        }
    } else if (b < 1232) {
        int i = (b - 1184) * 256 + tid;
        if (i < 10240) {
            int j = i & 7, lane = (i >> 3) & 63, g = i >> 9;  // g<20
            int kb = g >> 2, nf = g & 3;
            int o = nf * 16 + (lane & 15);
            int k = kb * 32 + (lane >> 4) * 8 + j;
            float v = (k < 133) ? Wd1[(size_t)o * 133 + k] : (k == 133 ? bd1[o] : 0.f);
            wd1f[i] = f2bf(v);
        } else if (i < 10240 + 2048) {
            int t = i - 10240;
            int j = t & 7, lane = (t >> 3) & 63, g = t >> 9;  // g<4
            int kb = g >> 1, nf = g & 1;
            int o = nf * 16 + (lane & 15);
            int k = kb * 32 + (lane >> 4) * 8 + j;
            wd2f[t] = f2bf(Wd2[(size_t)o * 64 + k]);
        }
    } else if (b < 9424) {
        int idx = (b - 1232) * 256 + tid;
        int n = idx >> 6, j = idx & 63;
        const float* wr = Wp + j * 23;
        const float* xr = x + (size_t)n * 12;
        float s = bp[j];
#pragma unroll
        for (int i = 0; i < 12; i++) s += xr[i] * wr[i];
#pragma unroll
        for (int i = 0; i < 11; i++) s += u[i] * wr[12 + i];
        hb[idx] = f2bf(tanhf(s));
    } else if (b < 17616) {
        int idx = (b - 9424) * 256 + tid;           // idx < 2^21
        int el = idx & 63, j = (idx >> 6) & 63, eb = idx >> 12;
        int e = eb * 64 + el;                       // lane-varying e -> coalesced
        float s = be1[j];
#pragma unroll
        for (int i = 0; i < 5; i++) s += ea[(size_t)e * 5 + i] * We1[j * 5 + i];
        hidT[(size_t)j * N_EDGES + e] = f2bf(s > 0.f ? s : 0.f);
    } else {
        int idx = (b - 17616) * 1024 + tid * 4;
        if (idx < 2129920) {
            float4v z = {0.f, 0.f, 0.f, 0.f};
            *(float4v*)(aggcnt + idx) = z;
        }
    }
}

__global__ __launch_bounds__(256) void k_counts(
    const int* __restrict__ ei, float* __restrict__ counts)
{
    int i = blockIdx.x * 256 + threadIdx.x;
    if (i < N_EDGES) atomicAdd(&counts[ei[N_EDGES + i]], 1.0f);
}

// ===================== fused msg GEMM ======================================
// 256 threads = 4 waves, 64 edges/block, grid 512 (2 blocks/CU, LDS 72KB).
// Wave w owns kk-slice w*16..w*16+15 (wave 3 also kk=64 = bias row, hv=1).
// Per kk: T[tile] = Hsrc(16x64) @ W2[kk](64x64) via 8 MFMA with STATIC bf16
// A-frags; acc += hid[e,kk] * T (v_fmac). B-frags reused across 4 M-tiles.
// Wave-private dbuf staging, counted vmcnt, no barriers until the reduce.
__global__ __launch_bounds__(256, 2) void k_msg_fused(
    const unsigned short* __restrict__ hidT,  // (64, E) bf16
    const unsigned short* __restrict__ hb,    // (N,64) bf16
    const unsigned short* __restrict__ w2tf,  // (66*4096) frag-interleaved
    const int* __restrict__ ei,
    float* __restrict__ agg)
{
    // LDS map: [0,65536) staging 4 waves x 2 dbuf x 8192B
    //          [65536,73728) hv strip: 4 waves x 16 r x 64 e bf16
    //          reduce overlay (after loop): [0,67584) 4 x 64 x 66 f32
    __shared__ __attribute__((aligned(16))) unsigned char smem[73728];
    unsigned short* stg = (unsigned short*)smem;
    unsigned short* hvl = (unsigned short*)(smem + 65536);
    float* red = (float*)smem;

    int tid = threadIdx.x, w = tid >> 6, lane = tid & 63;
    int l15 = lane & 15, quad = lane >> 4;
    int ebase = blockIdx.x * 64;
    int n = 16 + (w == 3 ? 1 : 0);   // wave 3 takes the bias row kk=64

    // ---- preamble: hv rows (coalesced 128B each) -> per-wave LDS strip ----
    {
        const unsigned short* hp = hidT + (size_t)(w * 16) * N_EDGES + ebase + lane;
        unsigned short* dp = hvl + (w * 16) * 64 + lane;
#pragma unroll
        for (int r = 0; r < 16; r++)
            dp[r * 64] = hp[(size_t)r * N_EDGES];
    }
    // ---- static A-frags: 4 edge-tiles x 2 K-halves of h[src] (bf16) ----
    short8 afr[4][2];
#pragma unroll
    for (int t = 0; t < 4; t++) {
        int src = ei[ebase + t * 16 + l15];
#pragma unroll
        for (int hh = 0; hh < 2; hh++)
            afr[t][hh] = *(const short8*)(hb + (size_t)src * 64 + hh * 32 + quad * 8);
    }

    unsigned short* wbuf = stg + w * (2 * 4096);
    auto stage = [&](int r, int db) {
        const unsigned short* g = w2tf + (size_t)(w * 16 + r) * 4096;
        unsigned short* d = wbuf + db * 4096;
#pragma unroll
        for (int c = 0; c < 8; c++)
            gload_lds16(g + c * 512 + lane * 8, d + c * 512);
    };

    stage(0, 0);
    stage(1, 1);

    float4v acc[4][4] = {};   // [tile][nf]
    for (int r = 0; r < n; r++) {
        int db = r & 1;
        // stage r complete when the newest 8 (stage r+1) may still be in flight
        if (r < n - 1) { asm volatile("s_waitcnt vmcnt(8)" ::: "memory"); }
        else           { asm volatile("s_waitcnt vmcnt(0)" ::: "memory"); }

        // B-frags for this kk (reused across the 4 M-tiles)
        short8 bfr[2][4];
        const unsigned short* bb = wbuf + db * 4096;
#pragma unroll
        for (int hh = 0; hh < 2; hh++)
#pragma unroll
            for (int nf = 0; nf < 4; nf++)
                bfr[hh][nf] = *(const short8*)(bb + (hh * 4 + nf) * 512 + lane * 8);

        // hv: 4 bf16 per tile (rows quad*4..+3), broadcast across l15
        bool bias = (r == 16);
        unsigned long long hu[4] = {0ull, 0ull, 0ull, 0ull};
        if (!bias) {
#pragma unroll
            for (int t = 0; t < 4; t++)
                hu[t] = *(const unsigned long long*)(hvl + (w * 16 + r) * 64 + t * 16 + quad * 4);
        }

        // all LDS reads done before overwriting buffer db with stage r+2
        asm volatile("s_waitcnt lgkmcnt(0)" ::: "memory");
        if (r + 2 < n) stage(r + 2, db);

#pragma unroll
        for (int t = 0; t < 4; t++) {
            float4v T[4];
#pragma unroll
            for (int nf = 0; nf < 4; nf++) {
                float4v z = {0.f, 0.f, 0.f, 0.f};
                T[nf] = __builtin_amdgcn_mfma_f32_16x16x32_bf16(afr[t][0], bfr[0][nf], z, 0, 0, 0);
            }
#pragma unroll
            for (int nf = 0; nf < 4; nf++)
                T[nf] = __builtin_amdgcn_mfma_f32_16x16x32_bf16(afr[t][1], bfr[1][nf], T[nf], 0, 0, 0);
#pragma unroll
            for (int rr = 0; rr < 4; rr++) {
                float hvv = bias ? 1.0f : bf2f((unsigned short)(hu[t] >> (16 * rr)));
#pragma unroll
                for (int nf = 0; nf < 4; nf++)
                    acc[t][nf][rr] += hvv * T[nf][rr];
            }
        }
    }

    // ---- cross-wave reduce (4 partials) + wave-coalesced atomic scatter ----
    __syncthreads();   // everyone done reading/staging LDS
    float* rp = red + w * 4224;                 // 64 rows x stride 66
#pragma unroll
    for (int t = 0; t < 4; t++)
#pragma unroll
        for (int nf = 0; nf < 4; nf++)
#pragma unroll
            for (int rr = 0; rr < 4; rr++)
                rp[(t * 16 + quad * 4 + rr) * 66 + nf * 16 + l15] = acc[t][nf][rr];
    __syncthreads();
    {
        // wave w -> rows w*16..w*16+15. Per atomic instruction the 64 lanes
        // cover 4 rows (quad) x 16 consecutive floats (l15) = 4 full 64B
        // lines -> L2 merges each line's 16 lanes into one RMW (this was the
        // R8 regression: row-per-lane gave 64 lines x 1 lane per instr).
        int dsts[4];
#pragma unroll
        for (int rr = 0; rr < 4; rr++)
            dsts[rr] = ei[N_EDGES + ebase + w * 16 + quad * 4 + rr];
#pragma unroll
        for (int nf = 0; nf < 4; nf++)
#pragma unroll
            for (int rr = 0; rr < 4; rr++) {
                int row = w * 16 + quad * 4 + rr;
                float s = 0.f;
#pragma unroll
                for (int ww = 0; ww < 4; ww++)
                    s += red[ww * 4224 + row * 66 + nf * 16 + l15];
                atomicAdd(agg + (size_t)dsts[rr] * 64 + nf * 16 + l15, s);
            }
    }
}

// ===================== fused node update ===================================
// h_old comes from hb (bf16) — fp32 h array eliminated.
__global__ __launch_bounds__(256) void k_node(
    const unsigned short* __restrict__ hb_in,
    const unsigned short* __restrict__ rootTf,
    const unsigned short* __restrict__ wcombf,
    float* __restrict__ agg, const float* __restrict__ counts,
    const float* __restrict__ conv_b,
    const float* __restrict__ bih, const float* __restrict__ bhh,
    unsigned short* __restrict__ hb_out)
{
    __shared__ unsigned short m_lds[64 * 72];
    int tid = threadIdx.x, w = tid >> 6, lane = tid & 63;
    int l15 = lane & 15, quad = lane >> 4;
    int node0 = blockIdx.x * 64;
    int row0 = w * 16;

    float4v acc1[4] = {};
    {
        short8 a1[2];
#pragma unroll
        for (int kb = 0; kb < 2; kb++)
            a1[kb] = *(const short8*)(hb_in + (size_t)(node0 + row0 + l15) * 64 + kb * 32 + quad * 8);
#pragma unroll
        for (int kb = 0; kb < 2; kb++)
#pragma unroll
            for (int nf = 0; nf < 4; nf++) {
                short8 b = *(const short8*)(rootTf + (size_t)((kb * 4 + nf) * 64 + lane) * 8);
                acc1[nf] = __builtin_amdgcn_mfma_f32_16x16x32_bf16(a1[kb], b, acc1[nf], 0, 0, 0);
            }
    }
#pragma unroll
    for (int rr = 0; rr < 4; rr++) {
        int nl = row0 + quad * 4 + rr;
        float cnt = counts[node0 + nl]; if (cnt < 1.f) cnt = 1.f;
        float rcp = 1.f / cnt;
#pragma unroll
        for (int nf = 0; nf < 4; nf++) {
            int c = nf * 16 + l15;
            float* ap = agg + (size_t)(node0 + nl) * 64 + c;
            float av = *ap;
            *ap = 0.f;
            float mv = av * rcp + acc1[nf][rr] + conv_b[c];
            m_lds[nl * 72 + c] = f2bf(mv > 0.f ? mv : 0.f);
        }
    }
    __syncthreads();

    float4v acc2[16] = {};
#pragma unroll
    for (int kb = 0; kb < 4; kb++) {
        short8 a2;
        if (kb < 2)
            a2 = *(const short8*)(m_lds + (row0 + l15) * 72 + kb * 32 + quad * 8);
        else
            a2 = *(const short8*)(hb_in + (size_t)(node0 + row0 + l15) * 64 + (kb - 2) * 32 + quad * 8);
#pragma unroll
        for (int nf = 0; nf < 16; nf++) {
            short8 b = *(const short8*)(wcombf + (size_t)((kb * 16 + nf) * 64 + lane) * 8);
            acc2[nf] = __builtin_amdgcn_mfma_f32_16x16x32_bf16(a2, b, acc2[nf], 0, 0, 0);
        }
    }

#pragma unroll
    for (int nf0 = 0; nf0 < 4; nf0++) {
        int c = nf0 * 16 + l15;
        float br = bih[c] + bhh[c];
        float bz = bih[64 + c] + bhh[64 + c];
        float bni = bih[128 + c], bnh = bhh[128 + c];
#pragma unroll
        for (int rr = 0; rr < 4; rr++) {
            int node = node0 + row0 + quad * 4 + rr;
            float gr = 1.f / (1.f + __expf(-(acc2[nf0][rr] + br)));
            float gz = 1.f / (1.f + __expf(-(acc2[nf0 + 4][rr] + bz)));
            float ng = tanhf(acc2[nf0 + 8][rr] + bni + gr * (acc2[nf0 + 12][rr] + bnh));
            float ho = bf2f(hb_in[(size_t)node * 64 + c]);
            float hn = (1.f - gz) * ng + gz * ho;
            hb_out[(size_t)node * 64 + c] = f2bf(hn);
        }
    }
}

// ===================== MFMA decoder ========================================
__global__ __launch_bounds__(256) void k_decoder(
    const unsigned short* __restrict__ hb, const int* __restrict__ ei,
    const float* __restrict__ ea,
    const unsigned short* __restrict__ wd1f, const unsigned short* __restrict__ wd2f,
    const float* __restrict__ bd2,
    const float* __restrict__ Wd3, const float* __restrict__ bd3,
    float* __restrict__ out)
{
    __shared__ unsigned short d1f[4][1024];  // per-wave: 2 frags x 512
    __shared__ float d2s[4][16 * 33];        // per-wave: 16 edges x 32 (+pad)
    int tid = threadIdx.x, w = tid >> 6, lane = tid & 63;
    int l15 = lane & 15, quad = lane >> 4;
    int ebase = blockIdx.x * 64 + w * 16;
    int e = ebase + l15;
    int src = ei[e], dst = ei[N_EDGES + e];

    short8 a[5];
#pragma unroll
    for (int kb = 0; kb < 2; kb++) {
        a[kb]     = *(const short8*)(hb + (size_t)src * 64 + kb * 32 + quad * 8);
        a[2 + kb] = *(const short8*)(hb + (size_t)dst * 64 + kb * 32 + quad * 8);
    }
    {
        union { short8 v; unsigned short u[8]; } tea;
#pragma unroll
        for (int j = 0; j < 8; j++) {
            float vv = 0.f;
            if (quad == 0) vv = (j < 5) ? ea[(size_t)e * 5 + j] : (j == 5 ? 1.f : 0.f);
            tea.u[j] = f2bf(vv);
        }
        a[4] = tea.v;
    }

    float4v acc1[4] = {};
#pragma unroll
    for (int kb = 0; kb < 5; kb++)
#pragma unroll
        for (int nf = 0; nf < 4; nf++) {
            short8 b = *(const short8*)(wd1f + (size_t)((kb * 4 + nf) * 64 + lane) * 8);
            acc1[nf] = __builtin_amdgcn_mfma_f32_16x16x32_bf16(a[kb], b, acc1[nf], 0, 0, 0);
        }
#pragma unroll
    for (int nf = 0; nf < 4; nf++) {
        int kbp = nf >> 1;
        int lanep_hi = ((nf & 1) * 2 + (l15 >> 3)) * 16;
        int jp = l15 & 7;
#pragma unroll
        for (int r = 0; r < 4; r++) {
            float v = acc1[nf][r];
            d1f[w][kbp * 512 + (lanep_hi + quad * 4 + r) * 8 + jp] = f2bf(v > 0.f ? v : 0.f);
        }
    }
    float4v acc2[2] = {};
#pragma unroll
    for (int kb = 0; kb < 2; kb++) {
        short8 a2 = *(const short8*)(&d1f[w][kb * 512 + lane * 8]);
#pragma unroll
        for (int nf = 0; nf < 2; nf++) {
            short8 b = *(const short8*)(wd2f + (size_t)((kb * 2 + nf) * 64 + lane) * 8);
            acc2[nf] = __builtin_amdgcn_mfma_f32_16x16x32_bf16(a2, b, acc2[nf], 0, 0, 0);
        }
    }
#pragma unroll
    for (int nf = 0; nf < 2; nf++) {
        int c = nf * 16 + l15;
        float bias = bd2[c];
#pragma unroll
        for (int r = 0; r < 4; r++) {
            float v = acc2[nf][r] + bias;
            d2s[w][(quad * 4 + r) * 33 + c] = v > 0.f ? v : 0.f;
        }
    }
    {
        int e_l = lane >> 2, t = lane & 3;
        float s = bd3[t];
        const float* w3 = Wd3 + t * 32;
        const float* dr = &d2s[w][e_l * 33];
#pragma unroll
        for (int k = 0; k < 32; k++) s += w3[k] * dr[k];
        out[(size_t)(ebase + e_l) * 4 + t] = s;
    }
}

extern "C" void kernel_launch(void* const* d_in, const int* in_sizes, int n_in,
                              void* d_out, int out_size, void* d_ws, size_t ws_size,
                              hipStream_t stream)
{
    const float* x      = (const float*)d_in[0];
    const int*   ei     = (const int*)d_in[1];
    const float* ea     = (const float*)d_in[2];
    const float* u      = (const float*)d_in[3];
    const float* Wp     = (const float*)d_in[4];
    const float* bp     = (const float*)d_in[5];
    const float* We1    = (const float*)d_in[6];
    const float* be1    = (const float*)d_in[7];
    const float* We2    = (const float*)d_in[8];
    const float* be2    = (const float*)d_in[9];
    const float* root   = (const float*)d_in[10];
    const float* conv_b = (const float*)d_in[11];
    const float* Wih    = (const float*)d_in[12];
    const float* bih    = (const float*)d_in[13];
    const float* Whh    = (const float*)d_in[14];
    const float* bhh    = (const float*)d_in[15];
    const float* Wd1    = (const float*)d_in[16];
    const float* bd1    = (const float*)d_in[17];
    const float* Wd2    = (const float*)d_in[18];
    const float* bd2    = (const float*)d_in[19];
    const float* Wd3    = (const float*)d_in[20];
    const float* bd3    = (const float*)d_in[21];
    float* out = (float*)d_out;

    char* ws = (char*)d_ws;
    size_t off = 0;
    auto take = [&](size_t bytes) -> char* {
        char* p = ws + off; off = (off + bytes + 255) & ~(size_t)255; return p;
    };
    unsigned short* hb     = (unsigned short*)take((size_t)N_NODES * 64 * 2);
    unsigned short* hidT   = (unsigned short*)take((size_t)N_EDGES * 64 * 2);
    // agg (2097152 f) and cnts (32768 f) contiguous: zeroed together in setup
    float*          aggcnt = (float*)take((size_t)(N_NODES * 64 + N_NODES) * 4);
    float*          agg    = aggcnt;
    float*          cnts   = aggcnt + (size_t)N_NODES * 64;
    unsigned short* w2tf   = (unsigned short*)take((size_t)66 * 4096 * 2);  // +1 pad blk
    unsigned short* rootTf = (unsigned short*)take((size_t)4096 * 2);
    unsigned short* wcombf = (unsigned short*)take((size_t)32768 * 2);
    unsigned short* wd1f   = (unsigned short*)take((size_t)10240 * 2);
    unsigned short* wd2f   = (unsigned short*)take((size_t)2048 * 2);
    (void)ws_size;

    k_setup<<<19696, 256, 0, stream>>>(root, Wih, Whh, We2, be2, Wd1, bd1, Wd2,
                                       x, u, Wp, bp, ea, We1, be1,
                                       rootTf, wcombf, w2tf, wd1f, wd2f,
                                       hb, hidT, aggcnt);
    k_counts<<<128, 256, 0, stream>>>(ei, cnts);

    for (int s = 0; s < STEPS; s++) {
        k_msg_fused<<<N_EDGES / 64, 256, 0, stream>>>(hidT, hb, w2tf, ei, agg);
        k_node<<<N_NODES / 64, 256, 0, stream>>>(hb, rootTf, wcombf, agg, cnts,
                                                 conv_b, bih, bhh, hb);
    }
    k_decoder<<<N_EDGES / 64, 256, 0, stream>>>(hb, ei, ea, wd1f, wd2f, bd2,
                                                Wd3, bd3, out);
}

// Round 3
// 259.698 us; speedup vs baseline: 2.2718x; 1.0016x over previous
//
#include <hip/hip_runtime.h>
#include <hip/hip_bf16.h>
#include <stdint.h>

// MPNN latency predictor, MI355X — round 10.
// vs R9: eliminate device-scope atomics from the steady state. Rationale:
// per-XCD L2s are not cross-coherent, so device-scope atomicAdd executes at
// the fabric/HBM side (R8's counters: WRITE_SIZE exactly 2^21 x 32B at
// 531 GB/s = the kernel ran at atomic-RMW speed). Even coalesced (R9), the
// ~2M lane atomics/dispatch cost ~15-20us of k_msg's ~28us.
//  * k_msg now stores per-edge messages to a dense msgbuf[E][64] with plain
//    coalesced dwordx4 stores (no scatter).
//  * one-time: k_scan (1-block prefix sum of counts) + k_scatter build a
//    dst-sorted edge-id list (eorder) with CSR offsets (off).
//  * k_node gathers+sums msgbuf rows per node (avg 1 edge/node), replacing
//    the agg read + re-zero; the agg buffer and its 8.5MB zero-fill die.
// k_msg main loop (kk-split waves, static A-frags, dbuf staging, counted
// vmcnt) unchanged from R9 to isolate the variable.

#define N_NODES 32768
#define N_EDGES 32768
#define STEPS 3

typedef __attribute__((ext_vector_type(8))) short short8;   // 8 bf16 = 4 VGPRs
typedef __attribute__((ext_vector_type(4))) float float4v;  // MFMA C/D

__device__ __forceinline__ float bf2f(unsigned short u) {
    union { unsigned int i; float f; } v; v.i = ((unsigned int)u) << 16; return v.f;
}
__device__ __forceinline__ unsigned short f2bf(float f) {  // RNE
    union { float f; unsigned int i; } v; v.f = f;
    unsigned int x = v.i;
    return (unsigned short)((x + 0x7fffu + ((x >> 16) & 1u)) >> 16);
}

// async global->LDS, 16B/lane; lds dest = wave-uniform base + lane*16
__device__ __forceinline__ void gload_lds16(const void* g, void* l) {
    __builtin_amdgcn_global_load_lds(
        (__attribute__((address_space(1))) void*)g,
        (__attribute__((address_space(3))) void*)l, 16, 0, 0);
}

// ===================== fused setup kernel ==================================
// blockIdx segments:
//  [0,144)       rootTf (4096) + wcombf (32768)      — frag-interleaved
//  [144,1184)    w2tf (266240 valid + 4096 pad)       — frag-interleaved
//  [1184,1232)   wd1f (10240) + wd2f (2048)           — frag-interleaved
//  [1232,9424)   proj: hb = bf16(tanh([x,u]@Wp^T+bp))
//  [9424,17616)  edge hidden TRANSPOSED: hidT[j][e] = relu(ea@We1^T+be1)
//  [17616,17648) zero cnts (32768 floats)
__global__ __launch_bounds__(256) void k_setup(
    const float* __restrict__ root, const float* __restrict__ Wih,
    const float* __restrict__ Whh,
    const float* __restrict__ We2, const float* __restrict__ be2,
    const float* __restrict__ Wd1, const float* __restrict__ bd1,
    const float* __restrict__ Wd2,
    const float* __restrict__ x, const float* __restrict__ u,
    const float* __restrict__ Wp, const float* __restrict__ bp,
    const float* __restrict__ ea, const float* __restrict__ We1,
    const float* __restrict__ be1,
    unsigned short* __restrict__ rootTf, unsigned short* __restrict__ wcombf,
    unsigned short* __restrict__ w2tf,
    unsigned short* __restrict__ wd1f, unsigned short* __restrict__ wd2f,
    unsigned short* __restrict__ hb,
    unsigned short* __restrict__ hidT, float* __restrict__ cnts)
{
    int b = blockIdx.x, tid = threadIdx.x;
    if (b < 144) {
        int i = b * 256 + tid;
        if (i < 4096) {
            int j = i & 7, lane = (i >> 3) & 63, g = i >> 9;   // g<8
            int kb = g >> 2, nf = g & 3;
            int o = nf * 16 + (lane & 15);
            int k = kb * 32 + (lane >> 4) * 8 + j;
            rootTf[i] = f2bf(root[k * 64 + o]);
        } else if (i < 4096 + 32768) {
            int t = i - 4096;
            int j = t & 7, lane = (t >> 3) & 63, g = t >> 9;   // g<64
            int kb = g >> 4, nf = g & 15;
            int cp = nf * 16 + (lane & 15);
            int k = kb * 32 + (lane >> 4) * 8 + j;
            float v;
            if (cp < 128)      v = (k < 64) ? Wih[cp * 64 + k] : Whh[cp * 64 + (k - 64)];
            else if (cp < 192) v = (k < 64) ? Wih[cp * 64 + k] : 0.f;
            else               v = (k < 64) ? 0.f : Whh[(cp - 64) * 64 + (k - 64)];
            wcombf[t] = f2bf(v);
        }
    } else if (b < 1184) {
        int t = (b - 144) * 256 + tid;   // t < 266240
        if (t < 65 * 4096) {
            int kk = t >> 12, r = t & 4095;
            int j = r & 7, lane = (r >> 3) & 63, g = r >> 9;  // g<8
            int half = g >> 2, nf = g & 3;
            int o = nf * 16 + (lane & 15);
            int hh = half * 32 + (lane >> 4) * 8 + j;
            float v = (kk < 64) ? We2[((size_t)(hh * 64 + o)) * 64 + kk]
                                : be2[(size_t)hh * 64 + o];
            w2tf[t] = f2bf(v);
        }
    } else if (b < 1232) {
        int i = (b - 1184) * 256 + tid;
        if (i < 10240) {
            int j = i & 7, lane = (i >> 3) & 63, g = i >> 9;  // g<20
            int kb = g >> 2, nf = g & 3;
            int o = nf * 16 + (lane & 15);
            int k = kb * 32 + (lane >> 4) * 8 + j;
            float v = (k < 133) ? Wd1[(size_t)o * 133 + k] : (k == 133 ? bd1[o] : 0.f);
            wd1f[i] = f2bf(v);
        } else if (i < 10240 + 2048) {
            int t = i - 10240;
            int j = t & 7, lane = (t >> 3) & 63, g = t >> 9;  // g<4
            int kb = g >> 1, nf = g & 1;
            int o = nf * 16 + (lane & 15);
            int k = kb * 32 + (lane >> 4) * 8 + j;
            wd2f[t] = f2bf(Wd2[(size_t)o * 64 + k]);
        }
    } else if (b < 9424) {
        int idx = (b - 1232) * 256 + tid;
        int n = idx >> 6, j = idx & 63;
        const float* wr = Wp + j * 23;
        const float* xr = x + (size_t)n * 12;
        float s = bp[j];
#pragma unroll
        for (int i = 0; i < 12; i++) s += xr[i] * wr[i];
#pragma unroll
        for (int i = 0; i < 11; i++) s += u[i] * wr[12 + i];
        hb[idx] = f2bf(tanhf(s));
    } else if (b < 17616) {
        int idx = (b - 9424) * 256 + tid;           // idx < 2^21
        int el = idx & 63, j = (idx >> 6) & 63, eb = idx >> 12;
        int e = eb * 64 + el;                       // lane-varying e -> coalesced
        float s = be1[j];
#pragma unroll
        for (int i = 0; i < 5; i++) s += ea[(size_t)e * 5 + i] * We1[j * 5 + i];
        hidT[(size_t)j * N_EDGES + e] = f2bf(s > 0.f ? s : 0.f);
    } else {
        int idx = (b - 17616) * 1024 + tid * 4;
        if (idx < 32768) {
            float4v z = {0.f, 0.f, 0.f, 0.f};
            *(float4v*)(cnts + idx) = z;
        }
    }
}

__global__ __launch_bounds__(256) void k_counts(
    const int* __restrict__ ei, float* __restrict__ counts)
{
    int i = blockIdx.x * 256 + threadIdx.x;
    if (i < N_EDGES) atomicAdd(&counts[ei[N_EDGES + i]], 1.0f);
}

// one-time exclusive prefix sum of counts -> off[0..N], plus working copy woff
__global__ __launch_bounds__(1024) void k_scan(
    const float* __restrict__ cnts, int* __restrict__ off, int* __restrict__ woff)
{
    __shared__ int part[1024];
    int t = threadIdx.x;
    int loc[32];
    int s = 0;
#pragma unroll
    for (int i = 0; i < 32; i++) { loc[i] = s; s += (int)cnts[t * 32 + i]; }
    part[t] = s;
    __syncthreads();
    for (int d = 1; d < 1024; d <<= 1) {
        int y = (t >= d) ? part[t - d] : 0;
        __syncthreads();
        part[t] += y;
        __syncthreads();
    }
    int pre = (t == 0) ? 0 : part[t - 1];
#pragma unroll
    for (int i = 0; i < 32; i++) {
        off[t * 32 + i] = pre + loc[i];
        woff[t * 32 + i] = pre + loc[i];
    }
    if (t == 1023) off[32768] = part[1023];
}

// one-time: place edge ids into dst-sorted slots (32K atomics, once)
__global__ __launch_bounds__(256) void k_scatter(
    const int* __restrict__ ei, int* __restrict__ woff, int* __restrict__ eorder)
{
    int e = blockIdx.x * 256 + threadIdx.x;
    if (e < N_EDGES) {
        int d = ei[N_EDGES + e];
        int slot = atomicAdd(&woff[d], 1);
        eorder[slot] = e;
    }
}

// ===================== fused msg GEMM ======================================
// 256 threads = 4 waves, 64 edges/block, grid 512 (2 blocks/CU, LDS 72KB).
// Wave w owns kk-slice w*16..w*16+15 (wave 3 also kk=64 = bias row, hv=1).
// Per kk: T[tile] = Hsrc(16x64) @ W2[kk](64x64) via 8 MFMA with STATIC bf16
// A-frags; acc += hid[e,kk] * T (v_fmac). B-frags reused across 4 M-tiles.
// Wave-private dbuf staging, counted vmcnt, no barriers until the reduce.
// Epilogue: cross-wave LDS reduce, then PLAIN coalesced stores to msgbuf.
__global__ __launch_bounds__(256, 2) void k_msg_fused(
    const unsigned short* __restrict__ hidT,  // (64, E) bf16
    const unsigned short* __restrict__ hb,    // (N,64) bf16
    const unsigned short* __restrict__ w2tf,  // (66*4096) frag-interleaved
    const int* __restrict__ ei,
    float* __restrict__ msgbuf)               // (E,64) f32 dense
{
    // LDS map: [0,65536) staging 4 waves x 2 dbuf x 8192B
    //          [65536,73728) hv strip: 4 waves x 16 r x 64 e bf16
    //          reduce overlay (after loop): [0,67584) 4 x 64 x 66 f32
    __shared__ __attribute__((aligned(16))) unsigned char smem[73728];
    unsigned short* stg = (unsigned short*)smem;
    unsigned short* hvl = (unsigned short*)(smem + 65536);
    float* red = (float*)smem;

    int tid = threadIdx.x, w = tid >> 6, lane = tid & 63;
    int l15 = lane & 15, quad = lane >> 4;
    int ebase = blockIdx.x * 64;
    int n = 16 + (w == 3 ? 1 : 0);   // wave 3 takes the bias row kk=64

    // ---- preamble: hv rows (coalesced 128B each) -> per-wave LDS strip ----
    {
        const unsigned short* hp = hidT + (size_t)(w * 16) * N_EDGES + ebase + lane;
        unsigned short* dp = hvl + (w * 16) * 64 + lane;
#pragma unroll
        for (int r = 0; r < 16; r++)
            dp[r * 64] = hp[(size_t)r * N_EDGES];
    }
    // ---- static A-frags: 4 edge-tiles x 2 K-halves of h[src] (bf16) ----
    short8 afr[4][2];
#pragma unroll
    for (int t = 0; t < 4; t++) {
        int src = ei[ebase + t * 16 + l15];
#pragma unroll
        for (int hh = 0; hh < 2; hh++)
            afr[t][hh] = *(const short8*)(hb + (size_t)src * 64 + hh * 32 + quad * 8);
    }

    unsigned short* wbuf = stg + w * (2 * 4096);
    auto stage = [&](int r, int db) {
        const unsigned short* g = w2tf + (size_t)(w * 16 + r) * 4096;
        unsigned short* d = wbuf + db * 4096;
#pragma unroll
        for (int c = 0; c < 8; c++)
            gload_lds16(g + (size_t)c * 512 + lane * 8, d + c * 512);
    };

    stage(0, 0);
    stage(1, 1);

    float4v acc[4][4] = {};   // [tile][nf]
    for (int r = 0; r < n; r++) {
        int db = r & 1;
        // stage r complete when the newest 8 (stage r+1) may still be in flight
        if (r < n - 1) { asm volatile("s_waitcnt vmcnt(8)" ::: "memory"); }
        else           { asm volatile("s_waitcnt vmcnt(0)" ::: "memory"); }

        // B-frags for this kk (reused across the 4 M-tiles)
        short8 bfr[2][4];
        const unsigned short* bb = wbuf + db * 4096;
#pragma unroll
        for (int hh = 0; hh < 2; hh++)
#pragma unroll
            for (int nf = 0; nf < 4; nf++)
                bfr[hh][nf] = *(const short8*)(bb + (hh * 4 + nf) * 512 + lane * 8);

        // hv: 4 bf16 per tile (rows quad*4..+3), broadcast across l15
        bool bias = (r == 16);
        unsigned long long hu[4] = {0ull, 0ull, 0ull, 0ull};
        if (!bias) {
#pragma unroll
            for (int t = 0; t < 4; t++)
                hu[t] = *(const unsigned long long*)(hvl + (w * 16 + r) * 64 + t * 16 + quad * 4);
        }

        // all LDS reads done before overwriting buffer db with stage r+2
        asm volatile("s_waitcnt lgkmcnt(0)" ::: "memory");
        if (r + 2 < n) stage(r + 2, db);

#pragma unroll
        for (int t = 0; t < 4; t++) {
            float4v T[4];
#pragma unroll
            for (int nf = 0; nf < 4; nf++) {
                float4v z = {0.f, 0.f, 0.f, 0.f};
                T[nf] = __builtin_amdgcn_mfma_f32_16x16x32_bf16(afr[t][0], bfr[0][nf], z, 0, 0, 0);
            }
#pragma unroll
            for (int nf = 0; nf < 4; nf++)
                T[nf] = __builtin_amdgcn_mfma_f32_16x16x32_bf16(afr[t][1], bfr[1][nf], T[nf], 0, 0, 0);
#pragma unroll
            for (int rr = 0; rr < 4; rr++) {
                float hvv = bias ? 1.0f : bf2f((unsigned short)(hu[t] >> (16 * rr)));
#pragma unroll
                for (int nf = 0; nf < 4; nf++)
                    acc[t][nf][rr] += hvv * T[nf][rr];
            }
        }
    }

    // ---- cross-wave reduce (4 partials) + plain coalesced store ----
    __syncthreads();   // everyone done reading/staging LDS
    float* rp = red + w * 4224;                 // 64 rows x stride 66
#pragma unroll
    for (int t = 0; t < 4; t++)
#pragma unroll
        for (int nf = 0; nf < 4; nf++)
#pragma unroll
            for (int rr = 0; rr < 4; rr++)
                rp[(t * 16 + quad * 4 + rr) * 66 + nf * 16 + l15] = acc[t][nf][rr];
    __syncthreads();
    {
        int row = tid >> 2, cg = tid & 3;
        float s[16];
#pragma unroll
        for (int k = 0; k < 16; k++) {
            float v = 0.f;
#pragma unroll
            for (int ww = 0; ww < 4; ww++)
                v += red[ww * 4224 + row * 66 + cg * 16 + k];
            s[k] = v;
        }
        float* op = msgbuf + (size_t)(ebase + row) * 64 + cg * 16;
#pragma unroll
        for (int q = 0; q < 4; q++) {
            float4v v4 = { s[4 * q], s[4 * q + 1], s[4 * q + 2], s[4 * q + 3] };
            *(float4v*)(op + 4 * q) = v4;
        }
    }
}

// ===================== fused node update ===================================
// Gathers msgbuf rows via dst-sorted edge list (no atomics, no agg buffer).
__global__ __launch_bounds__(256) void k_node(
    const unsigned short* __restrict__ hb_in,
    const unsigned short* __restrict__ rootTf,
    const unsigned short* __restrict__ wcombf,
    const float* __restrict__ msgbuf, const int* __restrict__ off,
    const int* __restrict__ eorder,
    const float* __restrict__ counts,
    const float* __restrict__ conv_b,
    const float* __restrict__ bih, const float* __restrict__ bhh,
    unsigned short* __restrict__ hb_out)
{
    __shared__ unsigned short m_lds[64 * 72];
    __shared__ float aggl[64 * 68];
    int tid = threadIdx.x, w = tid >> 6, lane = tid & 63;
    int l15 = lane & 15, quad = lane >> 4;
    int node0 = blockIdx.x * 64;
    int row0 = w * 16;

    // ---- gather-aggregate: 4 threads per node x 16 cols ----
    {
        int nl = tid >> 2, cg = tid & 3;
        int nn = node0 + nl;
        int s0 = off[nn], s1 = off[nn + 1];
        float acc[16] = {};
        for (int sl = s0; sl < s1; sl++) {
            int e = eorder[sl];
            const float* mr = msgbuf + (size_t)e * 64 + cg * 16;
#pragma unroll
            for (int q = 0; q < 4; q++) {
                float4v v = *(const float4v*)(mr + 4 * q);
#pragma unroll
                for (int j = 0; j < 4; j++) acc[4 * q + j] += v[j];
            }
        }
#pragma unroll
        for (int k = 0; k < 16; k++) aggl[nl * 68 + cg * 16 + k] = acc[k];
    }
    __syncthreads();

    float4v acc1[4] = {};
    {
        short8 a1[2];
#pragma unroll
        for (int kb = 0; kb < 2; kb++)
            a1[kb] = *(const short8*)(hb_in + (size_t)(node0 + row0 + l15) * 64 + kb * 32 + quad * 8);
#pragma unroll
        for (int kb = 0; kb < 2; kb++)
#pragma unroll
            for (int nf = 0; nf < 4; nf++) {
                short8 b = *(const short8*)(rootTf + (size_t)((kb * 4 + nf) * 64 + lane) * 8);
                acc1[nf] = __builtin_amdgcn_mfma_f32_16x16x32_bf16(a1[kb], b, acc1[nf], 0, 0, 0);
            }
    }
#pragma unroll
    for (int rr = 0; rr < 4; rr++) {
        int nl = row0 + quad * 4 + rr;
        float cnt = counts[node0 + nl]; if (cnt < 1.f) cnt = 1.f;
        float rcp = 1.f / cnt;
#pragma unroll
        for (int nf = 0; nf < 4; nf++) {
            int c = nf * 16 + l15;
            float av = aggl[nl * 68 + c];
            float mv = av * rcp + acc1[nf][rr] + conv_b[c];
            m_lds[nl * 72 + c] = f2bf(mv > 0.f ? mv : 0.f);
        }
    }
    __syncthreads();

    float4v acc2[16] = {};
#pragma unroll
    for (int kb = 0; kb < 4; kb++) {
        short8 a2;
        if (kb < 2)
            a2 = *(const short8*)(m_lds + (row0 + l15) * 72 + kb * 32 + quad * 8);
        else
            a2 = *(const short8*)(hb_in + (size_t)(node0 + row0 + l15) * 64 + (kb - 2) * 32 + quad * 8);
#pragma unroll
        for (int nf = 0; nf < 16; nf++) {
            short8 b = *(const short8*)(wcombf + (size_t)((kb * 16 + nf) * 64 + lane) * 8);
            acc2[nf] = __builtin_amdgcn_mfma_f32_16x16x32_bf16(a2, b, acc2[nf], 0, 0, 0);
        }
    }

#pragma unroll
    for (int nf0 = 0; nf0 < 4; nf0++) {
        int c = nf0 * 16 + l15;
        float br = bih[c] + bhh[c];
        float bz = bih[64 + c] + bhh[64 + c];
        float bni = bih[128 + c], bnh = bhh[128 + c];
#pragma unroll
        for (int rr = 0; rr < 4; rr++) {
            int node = node0 + row0 + quad * 4 + rr;
            float gr = 1.f / (1.f + __expf(-(acc2[nf0][rr] + br)));
            float gz = 1.f / (1.f + __expf(-(acc2[nf0 + 4][rr] + bz)));
            float ng = tanhf(acc2[nf0 + 8][rr] + bni + gr * (acc2[nf0 + 12][rr] + bnh));
            float ho = bf2f(hb_in[(size_t)node * 64 + c]);
            float hn = (1.f - gz) * ng + gz * ho;
            hb_out[(size_t)node * 64 + c] = f2bf(hn);
        }
    }
}

// ===================== MFMA decoder ========================================
__global__ __launch_bounds__(256) void k_decoder(
    const unsigned short* __restrict__ hb, const int* __restrict__ ei,
    const float* __restrict__ ea,
    const unsigned short* __restrict__ wd1f, const unsigned short* __restrict__ wd2f,
    const float* __restrict__ bd2,
    const float* __restrict__ Wd3, const float* __restrict__ bd3,
    float* __restrict__ out)
{
    __shared__ unsigned short d1f[4][1024];  // per-wave: 2 frags x 512
    __shared__ float d2s[4][16 * 33];        // per-wave: 16 edges x 32 (+pad)
    int tid = threadIdx.x, w = tid >> 6, lane = tid & 63;
    int l15 = lane & 15, quad = lane >> 4;
    int ebase = blockIdx.x * 64 + w * 16;
    int e = ebase + l15;
    int src = ei[e], dst = ei[N_EDGES + e];

    short8 a[5];
#pragma unroll
    for (int kb = 0; kb < 2; kb++) {
        a[kb]     = *(const short8*)(hb + (size_t)src * 64 + kb * 32 + quad * 8);
        a[2 + kb] = *(const short8*)(hb + (size_t)dst * 64 + kb * 32 + quad * 8);
    }
    {
        union { short8 v; unsigned short u[8]; } tea;
#pragma unroll
        for (int j = 0; j < 8; j++) {
            float vv = 0.f;
            if (quad == 0) vv = (j < 5) ? ea[(size_t)e * 5 + j] : (j == 5 ? 1.f : 0.f);
            tea.u[j] = f2bf(vv);
        }
        a[4] = tea.v;
    }

    float4v acc1[4] = {};
#pragma unroll
    for (int kb = 0; kb < 5; kb++)
#pragma unroll
        for (int nf = 0; nf < 4; nf++) {
            short8 b = *(const short8*)(wd1f + (size_t)((kb * 4 + nf) * 64 + lane) * 8);
            acc1[nf] = __builtin_amdgcn_mfma_f32_16x16x32_bf16(a[kb], b, acc1[nf], 0, 0, 0);
        }
#pragma unroll
    for (int nf = 0; nf < 4; nf++) {
        int kbp = nf >> 1;
        int lanep_hi = ((nf & 1) * 2 + (l15 >> 3)) * 16;
        int jp = l15 & 7;
#pragma unroll
        for (int r = 0; r < 4; r++) {
            float v = acc1[nf][r];
            d1f[w][kbp * 512 + (lanep_hi + quad * 4 + r) * 8 + jp] = f2bf(v > 0.f ? v : 0.f);
        }
    }
    float4v acc2[2] = {};
#pragma unroll
    for (int kb = 0; kb < 2; kb++) {
        short8 a2 = *(const short8*)(&d1f[w][kb * 512 + lane * 8]);
#pragma unroll
        for (int nf = 0; nf < 2; nf++) {
            short8 b = *(const short8*)(wd2f + (size_t)((kb * 2 + nf) * 64 + lane) * 8);
            acc2[nf] = __builtin_amdgcn_mfma_f32_16x16x32_bf16(a2, b, acc2[nf], 0, 0, 0);
        }
    }
#pragma unroll
    for (int nf = 0; nf < 2; nf++) {
        int c = nf * 16 + l15;
        float bias = bd2[c];
#pragma unroll
        for (int r = 0; r < 4; r++) {
            float v = acc2[nf][r] + bias;
            d2s[w][(quad * 4 + r) * 33 + c] = v > 0.f ? v : 0.f;
        }
    }
    {
        int e_l = lane >> 2, t = lane & 3;
        float s = bd3[t];
        const float* w3 = Wd3 + t * 32;
        const float* dr = &d2s[w][e_l * 33];
#pragma unroll
        for (int k = 0; k < 32; k++) s += w3[k] * dr[k];
        out[(size_t)(ebase + e_l) * 4 + t] = s;
    }
}

extern "C" void kernel_launch(void* const* d_in, const int* in_sizes, int n_in,
                              void* d_out, int out_size, void* d_ws, size_t ws_size,
                              hipStream_t stream)
{
    const float* x      = (const float*)d_in[0];
    const int*   ei     = (const int*)d_in[1];
    const float* ea     = (const float*)d_in[2];
    const float* u      = (const float*)d_in[3];
    const float* Wp     = (const float*)d_in[4];
    const float* bp     = (const float*)d_in[5];
    const float* We1    = (const float*)d_in[6];
    const float* be1    = (const float*)d_in[7];
    const float* We2    = (const float*)d_in[8];
    const float* be2    = (const float*)d_in[9];
    const float* root   = (const float*)d_in[10];
    const float* conv_b = (const float*)d_in[11];
    const float* Wih    = (const float*)d_in[12];
    const float* bih    = (const float*)d_in[13];
    const float* Whh    = (const float*)d_in[14];
    const float* bhh    = (const float*)d_in[15];
    const float* Wd1    = (const float*)d_in[16];
    const float* bd1    = (const float*)d_in[17];
    const float* Wd2    = (const float*)d_in[18];
    const float* bd2    = (const float*)d_in[19];
    const float* Wd3    = (const float*)d_in[20];
    const float* bd3    = (const float*)d_in[21];
    float* out = (float*)d_out;

    char* ws = (char*)d_ws;
    size_t off_b = 0;
    auto take = [&](size_t bytes) -> char* {
        char* p = ws + off_b; off_b = (off_b + bytes + 255) & ~(size_t)255; return p;
    };
    unsigned short* hb     = (unsigned short*)take((size_t)N_NODES * 64 * 2);
    unsigned short* hidT   = (unsigned short*)take((size_t)N_EDGES * 64 * 2);
    float*          msgbuf = (float*)take((size_t)N_EDGES * 64 * 4);
    float*          cnts   = (float*)take((size_t)N_NODES * 4);
    int*            off    = (int*)take((size_t)(N_NODES + 1) * 4);
    int*            woff   = (int*)take((size_t)N_NODES * 4);
    int*            eorder = (int*)take((size_t)N_EDGES * 4);
    unsigned short* w2tf   = (unsigned short*)take((size_t)66 * 4096 * 2);  // +1 pad blk
    unsigned short* rootTf = (unsigned short*)take((size_t)4096 * 2);
    unsigned short* wcombf = (unsigned short*)take((size_t)32768 * 2);
    unsigned short* wd1f   = (unsigned short*)take((size_t)10240 * 2);
    unsigned short* wd2f   = (unsigned short*)take((size_t)2048 * 2);
    (void)ws_size;

    k_setup<<<17648, 256, 0, stream>>>(root, Wih, Whh, We2, be2, Wd1, bd1, Wd2,
                                       x, u, Wp, bp, ea, We1, be1,
                                       rootTf, wcombf, w2tf, wd1f, wd2f,
                                       hb, hidT, cnts);
    k_counts<<<128, 256, 0, stream>>>(ei, cnts);
    k_scan<<<1, 1024, 0, stream>>>(cnts, off, woff);
    k_scatter<<<128, 256, 0, stream>>>(ei, woff, eorder);

    for (int s = 0; s < STEPS; s++) {
        k_msg_fused<<<N_EDGES / 64, 256, 0, stream>>>(hidT, hb, w2tf, ei, msgbuf);
        k_node<<<N_NODES / 64, 256, 0, stream>>>(hb, rootTf, wcombf, msgbuf, off,
                                                 eorder, cnts, conv_b, bih, bhh, hb);
    }
    k_decoder<<<N_EDGES / 64, 256, 0, stream>>>(hb, ei, ea, wd1f, wd2f, bd2,
                                                Wd3, bd3, out);
}